// Round 1
// baseline (261.281 us; speedup 1.0000x reference)
//
#include <hip/hip_runtime.h>

namespace {
constexpr int B = 4, C = 64, H = 128, W = 128, O = 64, KK = 9;
constexpr int WT = 32;              // pixels per block (one row segment)
constexpr int CH = 16;              // channels per K-chunk
constexpr int NCHUNK = C / CH;      // 4
constexpr int KC = CH * KK;         // 144
constexpr int WPAD = 68;            // o-dim pad: keeps 16B alignment for float4 reads
constexpr int THREADS = 256;
}

__global__ __launch_bounds__(THREADS, 2)
void deform_conv_fused(const float* __restrict__ x,
                       const float* __restrict__ offs,
                       const float* __restrict__ wgt,
                       float* __restrict__ out) {
  __shared__ int   s_i0[KK][WT];
  __shared__ int   s_j0[KK][WT];
  __shared__ float s_fi[KK][WT];
  __shared__ float s_fj[KK][WT];
  __shared__ float s_w[KC][WPAD];     // [c_local*KK + k][o]
  __shared__ float s_m[KC][WT + 1];   // [c_local*KK + k][pixel]

  const int t   = threadIdx.x;
  const int nwt = W / WT;                    // 4
  const int wt  = blockIdx.x % nwt;
  const int h   = (blockIdx.x / nwt) % H;
  const int b   = blockIdx.x / (nwt * H);
  const int w0  = wt * WT;

  // ---- Phase 0: sampling parameters, once per (tap, pixel), shared over C ----
  for (int idx = t; idx < KK * WT; idx += THREADS) {
    const int k = idx / WT, p = idx % WT;
    const int w = w0 + p;
    const float oi = offs[(((size_t)b * (2 * KK) + 2 * k    ) * H + h) * W + w];
    const float oj = offs[(((size_t)b * (2 * KK) + 2 * k + 1) * H + h) * W + w];
    const float ci = oi + (float)(h + (k / 3) - 1);
    const float cj = oj + (float)(w + (k % 3) - 1);
    const float fli = floorf(ci), flj = floorf(cj);
    s_i0[k][p] = (int)fli;
    s_j0[k][p] = (int)flj;
    s_fi[k][p] = ci - fli;
    s_fj[k][p] = cj - flj;
  }

  float acc[8];
#pragma unroll
  for (int i = 0; i < 8; ++i) acc[i] = 0.f;

  const int p  = t & (WT - 1);
  const int og = t >> 5;        // 0..7
  const int ob = og * 8;        // base output channel for this thread

  for (int cc = 0; cc < NCHUNK; ++cc) {
    const int c0 = cc * CH;
    __syncthreads();   // phase0 ready (cc=0) / previous GEMM done reading LDS

    // ---- weight chunk -> LDS: s_w[kidx][o] ----
    for (int idx = t; idx < O * KC; idx += THREADS) {
      const int o = idx / KC, kidx = idx % KC;   // kidx = c_local*KK + k
      s_w[kidx][o] = wgt[(size_t)o * (C * KK) + (size_t)c0 * KK + kidx];
    }

    // ---- bilinear gather chunk -> LDS: s_m[kidx][pixel] ----
    for (int idx = t; idx < CH * KK * WT; idx += THREADS) {
      const int pp   = idx & (WT - 1);
      const int rest = idx >> 5;           // WT == 32
      const int k    = rest % KK;
      const int cl   = rest / KK;
      const int i0 = s_i0[k][pp], j0 = s_j0[k][pp];
      const float fi = s_fi[k][pp], fj = s_fj[k][pp];
      const int i1 = i0 + 1, j1 = j0 + 1;
      const float* xb = x + (size_t)(b * C + c0 + cl) * H * W;
      const bool bi0 = (unsigned)i0 < (unsigned)H;
      const bool bi1 = (unsigned)i1 < (unsigned)H;
      const bool bj0 = (unsigned)j0 < (unsigned)W;
      const bool bj1 = (unsigned)j1 < (unsigned)W;
      const float v00 = (bi0 && bj0) ? xb[i0 * W + j0] : 0.f;
      const float v01 = (bi0 && bj1) ? xb[i0 * W + j1] : 0.f;
      const float v10 = (bi1 && bj0) ? xb[i1 * W + j0] : 0.f;
      const float v11 = (bi1 && bj1) ? xb[i1 * W + j1] : 0.f;
      const float top = v00 + fj * (v01 - v00);
      const float bot = v10 + fj * (v11 - v10);
      s_m[cl * KK + k][pp] = top + fi * (bot - top);
    }
    __syncthreads();

    // ---- register GEMM: 8 o-channels x 1 pixel per thread ----
#pragma unroll 4
    for (int k = 0; k < KC; ++k) {
      const float a = s_m[k][p];
      const float4 wv0 = *reinterpret_cast<const float4*>(&s_w[k][ob]);
      const float4 wv1 = *reinterpret_cast<const float4*>(&s_w[k][ob + 4]);
      acc[0] += a * wv0.x; acc[1] += a * wv0.y;
      acc[2] += a * wv0.z; acc[3] += a * wv0.w;
      acc[4] += a * wv1.x; acc[5] += a * wv1.y;
      acc[6] += a * wv1.z; acc[7] += a * wv1.w;
    }
  }

  // ---- epilogue: coalesced stores ----
#pragma unroll
  for (int i = 0; i < 8; ++i) {
    const int o = ob + i;
    out[(((size_t)b * O + o) * H + h) * W + w0 + p] = acc[i];
  }
}

extern "C" void kernel_launch(void* const* d_in, const int* in_sizes, int n_in,
                              void* d_out, int out_size, void* d_ws, size_t ws_size,
                              hipStream_t stream) {
  const float* x    = (const float*)d_in[0];
  const float* offs = (const float*)d_in[1];
  const float* wgt  = (const float*)d_in[2];
  float* out = (float*)d_out;
  const int grid = B * H * (W / WT);   // 2048 blocks
  deform_conv_fused<<<grid, THREADS, 0, stream>>>(x, offs, wgt, out);
}

// Round 2
// 41.464 us; speedup vs baseline: 6.3014x; 6.3014x over previous
//
#include <hip/hip_runtime.h>

namespace {
constexpr int B = 4, C = 64, H = 128, W = 128, O = 64, KK = 9;
constexpr int THREADS = 256;
constexpr size_t XT_BYTES = (size_t)B * H * W * C * 2;          // 16,777,216
constexpr size_t WF_BYTES = (size_t)KK * 2 * 4 * 64 * 8 * 2;    // 73,728
constexpr size_t WS_NEED  = XT_BYTES + WF_BYTES;
}

typedef float  f32x4 __attribute__((ext_vector_type(4)));
typedef short  s16x8 __attribute__((ext_vector_type(8)));

__device__ __forceinline__ float lo16(unsigned u) { return __uint_as_float(u << 16); }
__device__ __forceinline__ float hi16(unsigned u) { return __uint_as_float(u & 0xFFFF0000u); }
__device__ __forceinline__ unsigned bpack(float a, float b) {   // RNE bf16 pair
  unsigned ua = __float_as_uint(a); ua += 0x7FFFu + ((ua >> 16) & 1u);
  unsigned ub = __float_as_uint(b); ub += 0x7FFFu + ((ub >> 16) & 1u);
  return (ua >> 16) | (ub & 0xFFFF0000u);
}

// ---------- prep 1: x[b][c][h][w] f32 -> x_t[b][h][w][c] bf16 ----------
__global__ __launch_bounds__(THREADS)
void prep_transpose_x(const float* __restrict__ x, unsigned* __restrict__ xt_u32) {
  __shared__ float st[64][65];
  const int t = threadIdx.x;
  const int half = blockIdx.x & 1, h = (blockIdx.x >> 1) & 127, b = blockIdx.x >> 8;
  const int w0 = half * 64;
#pragma unroll
  for (int it = 0; it < 16; ++it) {
    const int w = t & 63, c = it * 4 + (t >> 6);
    st[w][c] = x[((size_t)(b * C + c) * H + h) * W + w0 + w];
  }
  __syncthreads();
#pragma unroll
  for (int it = 0; it < 8; ++it) {
    const int idx = it * THREADS + t;
    const int w = idx >> 5, c2 = (idx & 31) * 2;
    const unsigned p = bpack(st[w][c2], st[w][c2 + 1]);
    xt_u32[(size_t)(((b * H + h) * W) + w0 + w) * 32 + (c2 >> 1)] = p;
  }
}

// ---------- prep 2: weight -> bf16 A-fragment order ----------
// byte offset = ((((tap*2+ks)*4+mt)*64+lane)*8 + e) * 2
// o = mt*16 + (lane&15), c = ks*32 + (lane>>4)*8 + e, k_global = (tap, c)
__global__ __launch_bounds__(THREADS)
void prep_weight_frag(const float* __restrict__ wgt, unsigned short* __restrict__ wf) {
  const int gid = blockIdx.x * THREADS + threadIdx.x;
  if (gid >= KK * 2 * 4 * 64 * 8) return;
  const int e = gid & 7, lane = (gid >> 3) & 63, mt = (gid >> 9) & 3;
  const int ks = (gid >> 11) & 1, tap = gid >> 12;
  const int o = mt * 16 + (lane & 15);
  const int c = ks * 32 + ((lane >> 4) << 3) + e;
  const float v = wgt[(size_t)o * (C * KK) + c * KK + tap];
  unsigned u = __float_as_uint(v); u += 0x7FFFu + ((u >> 16) & 1u);
  wf[gid] = (unsigned short)(u >> 16);
}

// ---------- main: fused deform-sample + MFMA GEMM ----------
__global__ __launch_bounds__(THREADS, 2)
void deform_mfma(const float* __restrict__ offs, const char* __restrict__ xt,
                 const char* __restrict__ wf, float* __restrict__ out) {
  __shared__ float          s_p[4][KK][16][8];   // per-wave sampling params
  __shared__ unsigned short s_m[64 * 64];        // [block pix][c] bf16, XOR-swizzled

  const int t = threadIdx.x, l = t & 63, wid = t >> 6;
  const int half = blockIdx.x & 1, h = (blockIdx.x >> 1) & 127, b = blockIdx.x >> 8;
  const int w0 = half * 64;
  const int wbase = w0 + wid * 16;               // wave's first pixel (global w)

  // --- sampling params: this wave's 16 pixels x 9 taps ---
#pragma unroll
  for (int it = 0; it < 3; ++it) {
    const int item = it * 64 + l;
    if (item < KK * 16) {
      const int tap = item >> 4, pix = item & 15;
      const int ki = tap / 3, kj = tap - ki * 3;
      const int w = wbase + pix;
      const float* ob = offs + ((size_t)b * (2 * KK) + 2 * tap) * (H * W) + h * W + w;
      const float oi = ob[0], oj = ob[H * W];
      const float ci = oi + (float)(h + ki - 1);
      const float cj = oj + (float)(w + kj - 1);
      const float fli = floorf(ci), flj = floorf(cj);
      const int i0 = (int)fli, j0 = (int)flj, i1 = i0 + 1, j1 = j0 + 1;
      const float fi = ci - fli, fj = cj - flj, gi = 1.f - fi, gj = 1.f - fj;
      const bool bi0 = (unsigned)i0 < (unsigned)H, bi1 = (unsigned)i1 < (unsigned)H;
      const bool bj0 = (unsigned)j0 < (unsigned)W, bj1 = (unsigned)j1 < (unsigned)W;
      const int ic0 = min(max(i0, 0), H - 1), ic1 = min(max(i1, 0), H - 1);
      const int jc0 = min(max(j0, 0), W - 1), jc1 = min(max(j1, 0), W - 1);
      float* sp = &s_p[wid][tap][pix][0];
      sp[0] = gi * gj * (float)(bi0 && bj0);
      sp[1] = gi * fj * (float)(bi0 && bj1);
      sp[2] = fi * gj * (float)(bi1 && bj0);
      sp[3] = fi * fj * (float)(bi1 && bj1);
      sp[4] = __int_as_float(((b * H + ic0) * W + jc0) << 7);   // byte addr in x_t
      sp[5] = __int_as_float(((b * H + ic0) * W + jc1) << 7);
      sp[6] = __int_as_float(((b * H + ic1) * W + jc0) << 7);
      sp[7] = __int_as_float(((b * H + ic1) * W + jc1) << 7);
    }
  }

  f32x4 acc[4];
#pragma unroll
  for (int mt = 0; mt < 4; ++mt) acc[mt] = (f32x4)0.f;

  for (int tap = 0; tap < KK; ++tap) {
    // --- gather+lerp: wave's 16 pix x 64 c, 8 channels per lane ---
#pragma unroll
    for (int iter = 0; iter < 2; ++iter) {
      const int pix = (iter << 3) + (l >> 3);
      const int oct = l & 7;
      const float4 wv = *(const float4*)&s_p[wid][tap][pix][0];
      const float4 af = *(const float4*)&s_p[wid][tap][pix][4];
      const int ob = oct << 4;
      const uint4 v00 = *(const uint4*)(xt + __float_as_int(af.x) + ob);
      const uint4 v01 = *(const uint4*)(xt + __float_as_int(af.y) + ob);
      const uint4 v10 = *(const uint4*)(xt + __float_as_int(af.z) + ob);
      const uint4 v11 = *(const uint4*)(xt + __float_as_int(af.w) + ob);
      uint4 r;
      {
        float mlo, mhi;
        mlo = wv.x * lo16(v00.x) + wv.y * lo16(v01.x) + wv.z * lo16(v10.x) + wv.w * lo16(v11.x);
        mhi = wv.x * hi16(v00.x) + wv.y * hi16(v01.x) + wv.z * hi16(v10.x) + wv.w * hi16(v11.x);
        r.x = bpack(mlo, mhi);
        mlo = wv.x * lo16(v00.y) + wv.y * lo16(v01.y) + wv.z * lo16(v10.y) + wv.w * lo16(v11.y);
        mhi = wv.x * hi16(v00.y) + wv.y * hi16(v01.y) + wv.z * hi16(v10.y) + wv.w * hi16(v11.y);
        r.y = bpack(mlo, mhi);
        mlo = wv.x * lo16(v00.z) + wv.y * lo16(v01.z) + wv.z * lo16(v10.z) + wv.w * lo16(v11.z);
        mhi = wv.x * hi16(v00.z) + wv.y * hi16(v01.z) + wv.z * hi16(v10.z) + wv.w * hi16(v11.z);
        r.z = bpack(mlo, mhi);
        mlo = wv.x * lo16(v00.w) + wv.y * lo16(v01.w) + wv.z * lo16(v10.w) + wv.w * lo16(v11.w);
        mhi = wv.x * hi16(v00.w) + wv.y * hi16(v01.w) + wv.z * hi16(v10.w) + wv.w * hi16(v11.w);
        r.w = bpack(mlo, mhi);
      }
      const int row = (wid << 4) + pix;
      int byte = (row << 7) + (oct << 4);
      byte ^= ((row & 7) << 4);                      // T2 swizzle, 16B granularity
      *(uint4*)((char*)s_m + byte) = r;
    }

    // --- MFMA: 2 k-steps x 4 m-tiles ---
#pragma unroll
    for (int ks = 0; ks < 2; ++ks) {
      const int rr = (wid << 4) + (l & 15);
      int byte = (rr << 7) + (ks << 6) + ((l >> 4) << 4);
      byte ^= ((rr & 7) << 4);
      const s16x8 bfr = *(const s16x8*)((const char*)s_m + byte);
#pragma unroll
      for (int mt = 0; mt < 4; ++mt) {
        const s16x8 afr = *(const s16x8*)(wf + ((((tap * 2 + ks) * 4 + mt) * 64 + l) << 4));
        acc[mt] = __builtin_amdgcn_mfma_f32_16x16x32_bf16(afr, bfr, acc[mt], 0, 0, 0);
      }
    }
  }

  // --- epilogue ---
#pragma unroll
  for (int mt = 0; mt < 4; ++mt)
#pragma unroll
    for (int j = 0; j < 4; ++j) {
      const int o = mt * 16 + ((l >> 4) << 2) + j;
      out[((size_t)(b * O + o) * H + h) * W + wbase + (l & 15)] = acc[mt][j];
    }
}

// ---------- fallback (round-1 kernel, used only if ws too small) ----------
namespace fb {
constexpr int WT = 32, CH = 16, NCHUNK = 4, KC = 144, WPAD = 68;
}
__global__ __launch_bounds__(THREADS, 2)
void deform_conv_fused(const float* __restrict__ x, const float* __restrict__ offs,
                       const float* __restrict__ wgt, float* __restrict__ out) {
  using namespace fb;
  __shared__ int   s_i0[KK][WT];
  __shared__ int   s_j0[KK][WT];
  __shared__ float s_fi[KK][WT];
  __shared__ float s_fj[KK][WT];
  __shared__ float s_w[KC][WPAD];
  __shared__ float s_m[KC][WT + 1];
  const int t = threadIdx.x;
  const int nwt = W / WT;
  const int wt = blockIdx.x % nwt, h = (blockIdx.x / nwt) % H, b = blockIdx.x / (nwt * H);
  const int w0 = wt * WT;
  for (int idx = t; idx < KK * WT; idx += THREADS) {
    const int k = idx / WT, p = idx % WT, w = w0 + p;
    const float oi = offs[(((size_t)b * (2 * KK) + 2 * k) * H + h) * W + w];
    const float oj = offs[(((size_t)b * (2 * KK) + 2 * k + 1) * H + h) * W + w];
    const float ci = oi + (float)(h + (k / 3) - 1), cj = oj + (float)(w + (k % 3) - 1);
    const float fli = floorf(ci), flj = floorf(cj);
    s_i0[k][p] = (int)fli; s_j0[k][p] = (int)flj;
    s_fi[k][p] = ci - fli; s_fj[k][p] = cj - flj;
  }
  float acc[8];
#pragma unroll
  for (int i = 0; i < 8; ++i) acc[i] = 0.f;
  const int p = t & (WT - 1), ob = (t >> 5) * 8;
  for (int cc = 0; cc < NCHUNK; ++cc) {
    const int c0 = cc * CH;
    __syncthreads();
    for (int idx = t; idx < O * KC; idx += THREADS)
      s_w[idx % KC][idx / KC] = wgt[(size_t)(idx / KC) * (C * KK) + (size_t)c0 * KK + idx % KC];
    for (int idx = t; idx < CH * KK * WT; idx += THREADS) {
      const int pp = idx & (WT - 1), rest = idx >> 5, k = rest % KK, cl = rest / KK;
      const int i0 = s_i0[k][pp], j0 = s_j0[k][pp], i1 = i0 + 1, j1 = j0 + 1;
      const float fi = s_fi[k][pp], fj = s_fj[k][pp];
      const float* xb = x + (size_t)(b * C + c0 + cl) * H * W;
      const float v00 = ((unsigned)i0 < (unsigned)H && (unsigned)j0 < (unsigned)W) ? xb[i0 * W + j0] : 0.f;
      const float v01 = ((unsigned)i0 < (unsigned)H && (unsigned)j1 < (unsigned)W) ? xb[i0 * W + j1] : 0.f;
      const float v10 = ((unsigned)i1 < (unsigned)H && (unsigned)j0 < (unsigned)W) ? xb[i1 * W + j0] : 0.f;
      const float v11 = ((unsigned)i1 < (unsigned)H && (unsigned)j1 < (unsigned)W) ? xb[i1 * W + j1] : 0.f;
      const float top = v00 + fj * (v01 - v00), bot = v10 + fj * (v11 - v10);
      s_m[cl * KK + k][pp] = top + fi * (bot - top);
    }
    __syncthreads();
#pragma unroll 4
    for (int k = 0; k < KC; ++k) {
      const float a = s_m[k][p];
      const float4 wv0 = *reinterpret_cast<const float4*>(&s_w[k][ob]);
      const float4 wv1 = *reinterpret_cast<const float4*>(&s_w[k][ob + 4]);
      acc[0] += a * wv0.x; acc[1] += a * wv0.y; acc[2] += a * wv0.z; acc[3] += a * wv0.w;
      acc[4] += a * wv1.x; acc[5] += a * wv1.y; acc[6] += a * wv1.z; acc[7] += a * wv1.w;
    }
  }
#pragma unroll
  for (int i = 0; i < 8; ++i)
    out[(((size_t)b * O + ob + i) * H + h) * W + w0 + p] = acc[i];
}

extern "C" void kernel_launch(void* const* d_in, const int* in_sizes, int n_in,
                              void* d_out, int out_size, void* d_ws, size_t ws_size,
                              hipStream_t stream) {
  const float* x    = (const float*)d_in[0];
  const float* offs = (const float*)d_in[1];
  const float* wgt  = (const float*)d_in[2];
  float* out = (float*)d_out;

  if (ws_size < WS_NEED) {   // fallback: round-1 kernel
    deform_conv_fused<<<B * H * (W / 32), THREADS, 0, stream>>>(x, offs, wgt, out);
    return;
  }
  char* xt = (char*)d_ws;
  unsigned short* wf = (unsigned short*)(xt + XT_BYTES);

  prep_transpose_x<<<B * H * 2, THREADS, 0, stream>>>(x, (unsigned*)xt);
  prep_weight_frag<<<(KK * 2 * 4 * 64 * 8 + THREADS - 1) / THREADS, THREADS, 0, stream>>>(wgt, wf);
  deform_mfma<<<B * H * 2, THREADS, 0, stream>>>(offs, xt, (const char*)wf, out);
}